// Round 2
// baseline (1379.908 us; speedup 1.0000x reference)
//
#include <hip/hip_runtime.h>

#define H  1024
#define V  512
#define WV 300
#define S  64
#define N  512

// ---- workspace float offsets ----
#define WS_HALL   0                         // [S,H]
#define WS_CAT    (S*H)                     // [S,1536]  (hat | ac)
#define WS_W2V    (WS_CAT + S*1536)         // [S,H]
#define WS_CHOICE (WS_W2V + S*H)            // [S,2]
#define WS_SCAL   (WS_CHOICE + 2*S)         // [S]
#define WS_ACSUM  (WS_SCAL + S)             // [S]
#define WS_KT     (WS_ACSUM + S)            // [S,H]
#define WS_ATT    (WS_KT + S*H)             // [S,N]
#define WS_ACCUM  (WS_ATT + S*N)            // [3,H]
#define WS_ASUM   (WS_ACCUM + 3*H)          // [4]
#define WS_CTR    (WS_ASUM + 4)             // [1]

// ---- out float offsets ----
#define OUT_EP   0                  // [S,N]
#define OUT_AC   (S*N)              // [S,V]
#define OUT_SE   (S*N + S*V)        // [S,H]
#define OUT_ALL  (OUT_SE + S*H)     // [S,N,H]
#define OUT_ACT  (OUT_ALL + (size_t)S*N*H) // [S,WV]

__device__ __forceinline__ float wave_reduce(float v) {
#pragma unroll
  for (int m = 32; m > 0; m >>= 1) v += __shfl_xor(v, m, 64);
  return v;
}
__device__ __forceinline__ float dot4(float4 a, float4 b) {
  return a.x*b.x + a.y*b.y + a.z*b.z + a.w*b.w;
}

// ---------------------------------------------------------------------------
// Tiled NT GEMM: C[64, Nj] = X[64, K] @ W[Nj, K]^T + bias, optional activation.
// Block computes all 64 rows x 64 cols. act: 0 none, 1 relu, 2 sigmoid.
// Reads each W row once (vs 64x in the wave-per-output version).
// ---------------------------------------------------------------------------
#define KC 64
__global__ __launch_bounds__(256) void gemmNT(
    const float* __restrict__ X, int ldx,
    const float* __restrict__ W, const float* __restrict__ bias,
    int K, int act,
    float* __restrict__ out1, int ld1,
    float* __restrict__ out2, int ld2) {
  __shared__ float Xs[64][KC + 4];
  __shared__ float Ws[64][KC + 4];
  const int tid = threadIdx.x;
  const int tm = tid >> 5, tn = tid & 31;
  const int jbase = blockIdx.x * 64;
  float acc[8][2];
#pragma unroll
  for (int i = 0; i < 8; ++i) acc[i][0] = acc[i][1] = 0.f;
  const int lr = tid >> 2;          // staging: row 0..63
  const int lc = (tid & 3) * 16;    // 16 floats per thread
  for (int k0 = 0; k0 < K; k0 += KC) {
    const float4* xp = (const float4*)(X + (size_t)lr * ldx + k0 + lc);
    const float4* wp = (const float4*)(W + (size_t)(jbase + lr) * K + k0 + lc);
    float4 xv0 = xp[0], xv1 = xp[1], xv2 = xp[2], xv3 = xp[3];
    float4 wv0 = wp[0], wv1 = wp[1], wv2 = wp[2], wv3 = wp[3];
    __syncthreads();                 // previous chunk's compute done
    *(float4*)&Xs[lr][lc +  0] = xv0; *(float4*)&Xs[lr][lc +  4] = xv1;
    *(float4*)&Xs[lr][lc +  8] = xv2; *(float4*)&Xs[lr][lc + 12] = xv3;
    *(float4*)&Ws[lr][lc +  0] = wv0; *(float4*)&Ws[lr][lc +  4] = wv1;
    *(float4*)&Ws[lr][lc +  8] = wv2; *(float4*)&Ws[lr][lc + 12] = wv3;
    __syncthreads();
#pragma unroll
    for (int kk = 0; kk < KC; kk += 4) {
      float4 w0 = *(const float4*)&Ws[tn][kk];
      float4 w1 = *(const float4*)&Ws[tn + 32][kk];
#pragma unroll
      for (int i = 0; i < 8; ++i) {
        float4 x = *(const float4*)&Xs[tm * 8 + i][kk];
        acc[i][0] += dot4(x, w0);
        acc[i][1] += dot4(x, w1);
      }
    }
  }
  const int j0 = jbase + tn, j1 = jbase + tn + 32;
  const float b0 = bias[j0], b1 = bias[j1];
#pragma unroll
  for (int i = 0; i < 8; ++i) {
    const int r = tm * 8 + i;
    float v0 = acc[i][0] + b0;
    float v1 = acc[i][1] + b1;
    if (act == 1) { v0 = fmaxf(v0, 0.f); v1 = fmaxf(v1, 0.f); }
    else if (act == 2) {
      v0 = 1.f / (1.f + __expf(-v0));
      v1 = 1.f / (1.f + __expf(-v1));
    }
    out1[(size_t)r * ld1 + j0] = v0;
    out1[(size_t)r * ld1 + j1] = v1;
    if (out2) {
      out2[(size_t)r * ld2 + j0] = v0;
      out2[(size_t)r * ld2 + j1] = v1;
    }
  }
}

// choice softmax (c0,c1) and acsum. hat read from cat (stride 1536).
__global__ void k_choice(const float* __restrict__ cat, const float* __restrict__ out_ac,
                         const float* __restrict__ W3w, const float* __restrict__ W3b,
                         float* __restrict__ ws) {
  int t = blockIdx.x, tid = threadIdx.x;
  const float* hat = cat + (size_t)t * 1536;
  float4 h4 = *(const float4*)(hat + tid * 4);
  float p[4];
#pragma unroll
  for (int r = 0; r < 3; ++r) {
    float4 w4 = *(const float4*)(W3w + (size_t)r * H + tid * 4);
    p[r] = dot4(h4, w4);
  }
  const float* ac = out_ac + (size_t)t * V;
  p[3] = ac[tid * 2] + ac[tid * 2 + 1];
  __shared__ float red[4][256];
#pragma unroll
  for (int q = 0; q < 4; ++q) red[q][tid] = p[q];
  __syncthreads();
  for (int sft = 128; sft > 0; sft >>= 1) {
    if (tid < sft) {
#pragma unroll
      for (int q = 0; q < 4; ++q) red[q][tid] += red[q][tid + sft];
    }
    __syncthreads();
  }
  if (tid == 0) {
    float l0 = red[0][0] + W3b[0], l1 = red[1][0] + W3b[1], l2 = red[2][0] + W3b[2];
    float m  = fmaxf(l0, fmaxf(l1, l2));
    float e0 = __expf(l0 - m), e1 = __expf(l1 - m), e2 = __expf(l2 - m);
    float inv = 1.f / (e0 + e1 + e2);
    ws[WS_CHOICE + t * 2]     = e0 * inv;
    ws[WS_CHOICE + t * 2 + 1] = e1 * inv;
    ws[WS_ACSUM + t]          = red[3][0];
  }
}

// bar_ft = (ac/acsum)@emb -> out_act, plus scal = bar_ft@W4w + W4b (folded).
// One block per t; emb columns read coalesced across threads.
__global__ __launch_bounds__(256) void k_barft(
    const float* __restrict__ out_ac, const float* __restrict__ emb,
    const float* __restrict__ ws_ro, const float* __restrict__ W4w,
    const float* __restrict__ W4b, float* __restrict__ out_act,
    float* __restrict__ ws) {
  int t = blockIdx.x, tid = threadIdx.x;
  __shared__ float acS[V];
  const float* ac = out_ac + (size_t)t * V;
  acS[tid] = ac[tid];
  acS[tid + 256] = ac[tid + 256];
  __syncthreads();
  float s0 = 0.f, s1 = 0.f;
  const int w0 = tid, w1 = 256 + tid;
  for (int v = 0; v < V; ++v) {
    float a = acS[v];
    const float* er = emb + (size_t)v * WV;
    s0 += a * er[w0];
    if (tid < WV - 256) s1 += a * er[w1];
  }
  float inv = 1.f / ws_ro[WS_ACSUM + t];
  s0 *= inv; s1 *= inv;
  out_act[(size_t)t * WV + w0] = s0;
  if (tid < WV - 256) out_act[(size_t)t * WV + w1] = s1;
  float p = s0 * W4w[w0] + (tid < WV - 256 ? s1 * W4w[w1] : 0.f);
  __shared__ float red[256];
  red[tid] = p;
  __syncthreads();
  for (int s = 128; s > 0; s >>= 1) {
    if (tid < s) red[tid] += red[tid + s];
    __syncthreads();
  }
  if (tid == 0) ws[WS_SCAL + t] = red[0] + W4b[0];
}

// Sequential 64-step scan: ev in registers, NO out_all stores (deferred to
// k_recon). Stores per step: attn [8 floats/block], kt [4KB, block 0 only],
// out_ep, out_se. One grid barrier per step; reduction via fp32 atomics into
// 3-rotated [H] buffer.
__global__ __launch_bounds__(256) void k_seq(
    const float* __restrict__ ev0, const float* __restrict__ ws,
    float* __restrict__ accum, float* __restrict__ asum, unsigned* __restrict__ ctr,
    float* __restrict__ att, float* __restrict__ ktb,
    float* __restrict__ out_ep, float* __restrict__ out_se) {
  const int g = blockIdx.x, tid = threadIdx.x;
  const int lane = tid & 63, wv = tid >> 6;
  const int col = tid * 4;
  __shared__ float attnS[8], prevS[8], red[8][4];
  if (tid < 8) prevS[tid] = 0.f;
  float4 ev[8];
#pragma unroll
  for (int r = 0; r < 8; ++r)
    ev[r] = *(const float4*)(ev0 + (size_t)(g * 8 + r) * H + col);
  __syncthreads();
  unsigned target = 0;
  for (int t = 0; t < S; ++t) {
    const float4 w4 = *(const float4*)(ws + WS_W2V + (size_t)t * H + col);
    float dp[8];
#pragma unroll
    for (int r = 0; r < 8; ++r) dp[r] = dot4(ev[r], w4);
#pragma unroll
    for (int r = 0; r < 8; ++r) {
#pragma unroll
      for (int m = 32; m > 0; m >>= 1) dp[r] += __shfl_xor(dp[r], m, 64);
    }
    if (lane == 0) {
#pragma unroll
      for (int r = 0; r < 8; ++r) red[r][wv] = dp[r];
    }
    __syncthreads();
    if (tid < 8) {
      float d  = red[tid][0] + red[tid][1] + red[tid][2] + red[tid][3];
      float ep = 1.f / (1.f + __expf(-d));
      out_ep[(size_t)t * N + g * 8 + tid] = ep;
      float a = ws[WS_CHOICE + 2 * t] * ep + ws[WS_CHOICE + 2 * t + 1] * prevS[tid];
      prevS[tid] = ep;
      attnS[tid] = a;
      att[(size_t)t * N + g * 8 + tid] = a;
    }
    __syncthreads();
    float at[8];
#pragma unroll
    for (int r = 0; r < 8; ++r) at[r] = attnS[r];
    float4 pv = make_float4(0.f, 0.f, 0.f, 0.f);
#pragma unroll
    for (int r = 0; r < 8; ++r) {
      pv.x += at[r] * ev[r].x; pv.y += at[r] * ev[r].y;
      pv.z += at[r] * ev[r].z; pv.w += at[r] * ev[r].w;
    }
    float* acc = accum + (t % 3) * H;
    atomicAdd(acc + col + 0, pv.x);
    atomicAdd(acc + col + 1, pv.y);
    atomicAdd(acc + col + 2, pv.z);
    atomicAdd(acc + col + 3, pv.w);
    if (tid == 0) {
      float pa = 0.f;
#pragma unroll
      for (int r = 0; r < 8; ++r) pa += at[r];
      atomicAdd(asum + (t % 3), pa);
    }
    // ---- grid barrier (release/acquire supplies the ordering) ----
    __syncthreads();
    target += (unsigned)gridDim.x;
    if (tid == 0) {
      __hip_atomic_fetch_add(ctr, 1u, __ATOMIC_RELEASE, __HIP_MEMORY_SCOPE_AGENT);
      while (__hip_atomic_load(ctr, __ATOMIC_ACQUIRE, __HIP_MEMORY_SCOPE_AGENT) < target)
        __builtin_amdgcn_s_sleep(2);
    }
    __syncthreads();
    // ---- phase 2: reduced bar_et -> kt; update ev registers ----
    float asv = __hip_atomic_load(asum + (t % 3), __ATOMIC_RELAXED, __HIP_MEMORY_SCOPE_AGENT);
    float4 pvs;
    pvs.x = __hip_atomic_load(acc + col + 0, __ATOMIC_RELAXED, __HIP_MEMORY_SCOPE_AGENT);
    pvs.y = __hip_atomic_load(acc + col + 1, __ATOMIC_RELAXED, __HIP_MEMORY_SCOPE_AGENT);
    pvs.z = __hip_atomic_load(acc + col + 2, __ATOMIC_RELAXED, __HIP_MEMORY_SCOPE_AGENT);
    pvs.w = __hip_atomic_load(acc + col + 3, __ATOMIC_RELAXED, __HIP_MEMORY_SCOPE_AGENT);
    float inv = 1.f / asv;
    float4 bar = make_float4(pvs.x * inv, pvs.y * inv, pvs.z * inv, pvs.w * inv);
    float sc = ws[WS_SCAL + t];
    float4 kt = make_float4(fmaxf(sc * bar.x, 0.f), fmaxf(sc * bar.y, 0.f),
                            fmaxf(sc * bar.z, 0.f), fmaxf(sc * bar.w, 0.f));
    if (g == 0) {
      *(float4*)(out_se + (size_t)t * H + col) = bar;
      *(float4*)(ktb + (size_t)t * H + col) = kt;
    }
    if (tid < 16)
      __hip_atomic_store(accum + ((t + 2) % 3) * H + g * 16 + tid, 0.f,
                         __ATOMIC_RELAXED, __HIP_MEMORY_SCOPE_AGENT);
    if (g == 0 && tid == 16)
      __hip_atomic_store(asum + ((t + 2) % 3), 0.f, __ATOMIC_RELAXED, __HIP_MEMORY_SCOPE_AGENT);
#pragma unroll
    for (int r = 0; r < 8; ++r) {
      float a = at[r];
      ev[r].x = a * kt.x + (1.f - a) * ev[r].x;
      ev[r].y = a * kt.y + (1.f - a) * ev[r].y;
      ev[r].z = a * kt.z + (1.f - a) * ev[r].z;
      ev[r].w = a * kt.w + (1.f - a) * ev[r].w;
    }
  }
}

// Reconstruct out_all[t,n,:] from ev0, attn, kt: per-row affine scan,
// fully parallel over (n, col). 512 blocks x 256 threads, float4 per thread.
__global__ __launch_bounds__(256) void k_recon(
    const float* __restrict__ ev0, const float* __restrict__ att,
    const float* __restrict__ ktb, float* __restrict__ out_all) {
  const int n = blockIdx.x, tid = threadIdx.x;
  const int col = tid * 4;
  __shared__ float aS[S];
  if (tid < S) aS[tid] = att[(size_t)tid * N + n];
  float4 v = *(const float4*)(ev0 + (size_t)n * H + col);
  __syncthreads();
  for (int t = 0; t < S; ++t) {
    float a = aS[t];
    float4 k4 = *(const float4*)(ktb + (size_t)t * H + col);
    v.x = a * k4.x + (1.f - a) * v.x;
    v.y = a * k4.y + (1.f - a) * v.y;
    v.z = a * k4.z + (1.f - a) * v.z;
    v.w = a * k4.w + (1.f - a) * v.w;
    *(float4*)(out_all + ((size_t)t * N + n) * H + col) = v;
  }
}

extern "C" void kernel_launch(void* const* d_in, const int* in_sizes, int n_in,
                              void* d_out, int out_size, void* d_ws, size_t ws_size,
                              hipStream_t stream) {
  const float* vv  = (const float*)d_in[0];
  const float* ev0 = (const float*)d_in[1];
  const float* A1w = (const float*)d_in[2];
  const float* A1b = (const float*)d_in[3];
  const float* A2w = (const float*)d_in[4];
  const float* A2b = (const float*)d_in[5];
  const float* emb = (const float*)d_in[6];
  const float* W1w = (const float*)d_in[7];
  const float* W1b = (const float*)d_in[8];
  const float* W2w = (const float*)d_in[9];
  const float* W2b = (const float*)d_in[10];
  const float* W3w = (const float*)d_in[11];
  const float* W3b = (const float*)d_in[12];
  const float* W4w = (const float*)d_in[13];
  const float* W4b = (const float*)d_in[14];

  float* ws  = (float*)d_ws;
  float* out = (float*)d_out;
  float* out_ep  = out + OUT_EP;
  float* out_ac  = out + OUT_AC;
  float* out_se  = out + OUT_SE;
  float* out_all = out + OUT_ALL;
  float* out_act = out + OUT_ACT;
  float* cat = ws + WS_CAT;

  // zero accum/asum/barrier counter (rest of ws is write-before-read)
  hipMemsetAsync(ws + WS_ACCUM, 0, (size_t)(3 * H + 5) * sizeof(float), stream);

  // Hall = relu(vv@A1w^T+A1b)
  gemmNT<<<16, 256, 0, stream>>>(vv, H, A1w, A1b, H, 1, ws + WS_HALL, H, (float*)nullptr, 0);
  // hat  = relu(vv@W1w^T+W1b) -> cat[:, :1024]
  gemmNT<<<16, 256, 0, stream>>>(vv, H, W1w, W1b, H, 1, cat, 1536, (float*)nullptr, 0);
  // ac   = sigmoid(Hall@A2w^T+A2b) -> out_ac and cat[:, 1024:]
  gemmNT<<<8, 256, 0, stream>>>(ws + WS_HALL, H, A2w, A2b, H, 2, out_ac, V, cat + H, 1536);
  // choice softmax + acsum
  k_choice<<<S, 256, 0, stream>>>(cat, out_ac, W3w, W3b, ws);
  // w2v = cat@W2w^T + W2b
  gemmNT<<<16, 256, 0, stream>>>(cat, 1536, W2w, W2b, 1536, 0, ws + WS_W2V, H, (float*)nullptr, 0);
  // bar_ft (+ scal folded)
  k_barft<<<S, 256, 0, stream>>>(out_ac, emb, ws, W4w, W4b, out_act, ws);
  // sequential scan (scalars only)
  k_seq<<<64, 256, 0, stream>>>(ev0, ws, ws + WS_ACCUM, ws + WS_ASUM,
                                (unsigned*)(ws + WS_CTR),
                                ws + WS_ATT, ws + WS_KT, out_ep, out_se);
  // parallel reconstruction of out_all
  k_recon<<<N, 256, 0, stream>>>(ev0, ws + WS_ATT, ws + WS_KT, out_all);
}

// Round 3
// 1267.441 us; speedup vs baseline: 1.0887x; 1.0887x over previous
//
#include <hip/hip_runtime.h>

#define H  1024
#define V  512
#define WV 300
#define S  64
#define N  512

// ---- workspace float offsets ----
#define WS_HALL   0                         // [S,H]
#define WS_CAT    (S*H)                     // [S,1536]  (hat | ac)
#define WS_W2V    (WS_CAT + S*1536)         // [S,H]
#define WS_CHOICE (WS_W2V + S*H)            // [S,2]
#define WS_SCAL   (WS_CHOICE + 2*S)         // [S]
#define WS_ACSUM  (WS_SCAL + S)             // [S]
#define WS_KT     (WS_ACSUM + S)            // [S,H]
#define WS_ATT    (WS_KT + S*H)             // [S,N]
#define WS_ACCUM  (WS_ATT + S*N)            // [3,H]
#define WS_ASUM   (WS_ACCUM + 3*H)          // [4]
#define WS_CTR    (WS_ASUM + 4)             // [1]

// ---- out float offsets ----
#define OUT_EP   0                  // [S,N]
#define OUT_AC   (S*N)              // [S,V]
#define OUT_SE   (S*N + S*V)        // [S,H]
#define OUT_ALL  (OUT_SE + S*H)     // [S,N,H]
#define OUT_ACT  (OUT_ALL + (size_t)S*N*H) // [S,WV]

__device__ __forceinline__ float dot4(float4 a, float4 b) {
  return a.x*b.x + a.y*b.y + a.z*b.z + a.w*b.w;
}

// ---------------------------------------------------------------------------
// Pipelined tiled NT GEMM: C[64, 64-tile] = X[64,K] @ W[j,:K]^T + bias, act.
// blockIdx.x = 64-col tile, blockIdx.y = matrix select (0/1) for fused launch.
// Software pipeline: next K-chunk's global loads issue BEFORE current chunk's
// compute so HBM latency hides under FMA work.
// ---------------------------------------------------------------------------
struct GArgs {
  const float* X; const float* W0; const float* W1;
  const float* B0; const float* B1;
  float* o1_0; float* o1_1; float* o2_0; float* o2_1;
  int ldx, K, act, ld1_0, ld1_1, ld2_0, ld2_1;
};

#define KC 64
__global__ __launch_bounds__(256) void gemmNT(GArgs a) {
  __shared__ float Xs[64][KC + 4];
  __shared__ float Ws[64][KC + 4];
  const int tid = threadIdx.x;
  const int m = blockIdx.y;
  const float* W    = m ? a.W1 : a.W0;
  const float* bias = m ? a.B1 : a.B0;
  float* out1 = m ? a.o1_1 : a.o1_0;
  float* out2 = m ? a.o2_1 : a.o2_0;
  const int ld1 = m ? a.ld1_1 : a.ld1_0;
  const int ld2 = m ? a.ld2_1 : a.ld2_0;
  const int K = a.K;

  const int tm = tid >> 5, tn = tid & 31;
  const int jbase = blockIdx.x * 64;
  float acc[8][2];
#pragma unroll
  for (int i = 0; i < 8; ++i) acc[i][0] = acc[i][1] = 0.f;
  const int lr = tid >> 2;
  const int lc = (tid & 3) * 16;
  const float* xrow = a.X + (size_t)lr * a.ldx + lc;
  const float* wrow = W + (size_t)(jbase + lr) * K + lc;
  float4 xv0, xv1, xv2, xv3, wv0, wv1, wv2, wv3;
  // prefetch chunk 0
  xv0 = ((const float4*)xrow)[0]; xv1 = ((const float4*)xrow)[1];
  xv2 = ((const float4*)xrow)[2]; xv3 = ((const float4*)xrow)[3];
  wv0 = ((const float4*)wrow)[0]; wv1 = ((const float4*)wrow)[1];
  wv2 = ((const float4*)wrow)[2]; wv3 = ((const float4*)wrow)[3];
  for (int k0 = 0; k0 < K; k0 += KC) {
    __syncthreads();                 // previous chunk's compute done
    *(float4*)&Xs[lr][lc +  0] = xv0; *(float4*)&Xs[lr][lc +  4] = xv1;
    *(float4*)&Xs[lr][lc +  8] = xv2; *(float4*)&Xs[lr][lc + 12] = xv3;
    *(float4*)&Ws[lr][lc +  0] = wv0; *(float4*)&Ws[lr][lc +  4] = wv1;
    *(float4*)&Ws[lr][lc +  8] = wv2; *(float4*)&Ws[lr][lc + 12] = wv3;
    __syncthreads();
    if (k0 + KC < K) {               // issue NEXT chunk loads before compute
      const float* xp = xrow + k0 + KC;
      const float* wp = wrow + k0 + KC;
      xv0 = ((const float4*)xp)[0]; xv1 = ((const float4*)xp)[1];
      xv2 = ((const float4*)xp)[2]; xv3 = ((const float4*)xp)[3];
      wv0 = ((const float4*)wp)[0]; wv1 = ((const float4*)wp)[1];
      wv2 = ((const float4*)wp)[2]; wv3 = ((const float4*)wp)[3];
    }
#pragma unroll
    for (int kk = 0; kk < KC; kk += 4) {
      float4 w0 = *(const float4*)&Ws[tn][kk];
      float4 w1 = *(const float4*)&Ws[tn + 32][kk];
#pragma unroll
      for (int i = 0; i < 8; ++i) {
        float4 x = *(const float4*)&Xs[tm * 8 + i][kk];
        acc[i][0] += dot4(x, w0);
        acc[i][1] += dot4(x, w1);
      }
    }
  }
  const int j0 = jbase + tn, j1 = jbase + tn + 32;
  const float b0 = bias[j0], b1 = bias[j1];
#pragma unroll
  for (int i = 0; i < 8; ++i) {
    const int r = tm * 8 + i;
    float v0 = acc[i][0] + b0;
    float v1 = acc[i][1] + b1;
    if (a.act == 1) { v0 = fmaxf(v0, 0.f); v1 = fmaxf(v1, 0.f); }
    else if (a.act == 2) {
      v0 = 1.f / (1.f + __expf(-v0));
      v1 = 1.f / (1.f + __expf(-v1));
    }
    out1[(size_t)r * ld1 + j0] = v0;
    out1[(size_t)r * ld1 + j1] = v1;
    if (out2) {
      out2[(size_t)r * ld2 + j0] = v0;
      out2[(size_t)r * ld2 + j1] = v1;
    }
  }
}

// choice softmax (c0,c1) and acsum. hat read from cat (stride 1536).
__global__ void k_choice(const float* __restrict__ cat, const float* __restrict__ out_ac,
                         const float* __restrict__ W3w, const float* __restrict__ W3b,
                         float* __restrict__ ws) {
  int t = blockIdx.x, tid = threadIdx.x;
  const float* hat = cat + (size_t)t * 1536;
  float4 h4 = *(const float4*)(hat + tid * 4);
  float p[4];
#pragma unroll
  for (int r = 0; r < 3; ++r) {
    float4 w4 = *(const float4*)(W3w + (size_t)r * H + tid * 4);
    p[r] = dot4(h4, w4);
  }
  const float* ac = out_ac + (size_t)t * V;
  p[3] = ac[tid * 2] + ac[tid * 2 + 1];
  __shared__ float red[4][256];
#pragma unroll
  for (int q = 0; q < 4; ++q) red[q][tid] = p[q];
  __syncthreads();
  for (int sft = 128; sft > 0; sft >>= 1) {
    if (tid < sft) {
#pragma unroll
      for (int q = 0; q < 4; ++q) red[q][tid] += red[q][tid + sft];
    }
    __syncthreads();
  }
  if (tid == 0) {
    float l0 = red[0][0] + W3b[0], l1 = red[1][0] + W3b[1], l2 = red[2][0] + W3b[2];
    float m  = fmaxf(l0, fmaxf(l1, l2));
    float e0 = __expf(l0 - m), e1 = __expf(l1 - m), e2 = __expf(l2 - m);
    float inv = 1.f / (e0 + e1 + e2);
    ws[WS_CHOICE + t * 2]     = e0 * inv;
    ws[WS_CHOICE + t * 2 + 1] = e1 * inv;
    ws[WS_ACSUM + t]          = red[3][0];
  }
}

// bar_ft = (ac/acsum)@emb -> out_act, plus scal = bar_ft@W4w + W4b (folded).
__global__ __launch_bounds__(256) void k_barft(
    const float* __restrict__ out_ac, const float* __restrict__ emb,
    const float* __restrict__ ws_ro, const float* __restrict__ W4w,
    const float* __restrict__ W4b, float* __restrict__ out_act,
    float* __restrict__ ws) {
  int t = blockIdx.x, tid = threadIdx.x;
  __shared__ float acS[V];
  const float* ac = out_ac + (size_t)t * V;
  acS[tid] = ac[tid];
  acS[tid + 256] = ac[tid + 256];
  __syncthreads();
  float s0 = 0.f, s1 = 0.f;
  const int w0 = tid, w1 = 256 + tid;
  for (int v = 0; v < V; ++v) {
    float a = acS[v];
    const float* er = emb + (size_t)v * WV;
    s0 += a * er[w0];
    if (tid < WV - 256) s1 += a * er[w1];
  }
  float inv = 1.f / ws_ro[WS_ACSUM + t];
  s0 *= inv; s1 *= inv;
  out_act[(size_t)t * WV + w0] = s0;
  if (tid < WV - 256) out_act[(size_t)t * WV + w1] = s1;
  float p = s0 * W4w[w0] + (tid < WV - 256 ? s1 * W4w[w1] : 0.f);
  __shared__ float red[256];
  red[tid] = p;
  __syncthreads();
  for (int s = 128; s > 0; s >>= 1) {
    if (tid < s) red[tid] += red[tid + s];
    __syncthreads();
  }
  if (tid == 0) ws[WS_SCAL + t] = red[0] + W4b[0];
}

// Sequential 64-step scan: ev in registers; per-step stores only attn/kt/out_ep/
// out_se. One grid barrier per step — RELAXED polling (no per-iteration cache
// invalidate), single ACQUIRE on exit.
__global__ __launch_bounds__(256) void k_seq(
    const float* __restrict__ ev0, const float* __restrict__ ws,
    float* __restrict__ accum, float* __restrict__ asum, unsigned* __restrict__ ctr,
    float* __restrict__ att, float* __restrict__ ktb,
    float* __restrict__ out_ep, float* __restrict__ out_se) {
  const int g = blockIdx.x, tid = threadIdx.x;
  const int lane = tid & 63, wv = tid >> 6;
  const int col = tid * 4;
  __shared__ float attnS[8], prevS[8], red[8][4];
  if (tid < 8) prevS[tid] = 0.f;
  float4 ev[8];
#pragma unroll
  for (int r = 0; r < 8; ++r)
    ev[r] = *(const float4*)(ev0 + (size_t)(g * 8 + r) * H + col);
  __syncthreads();
  unsigned target = 0;
  for (int t = 0; t < S; ++t) {
    const float4 w4 = *(const float4*)(ws + WS_W2V + (size_t)t * H + col);
    float dp[8];
#pragma unroll
    for (int r = 0; r < 8; ++r) dp[r] = dot4(ev[r], w4);
#pragma unroll
    for (int r = 0; r < 8; ++r) {
#pragma unroll
      for (int m = 32; m > 0; m >>= 1) dp[r] += __shfl_xor(dp[r], m, 64);
    }
    if (lane == 0) {
#pragma unroll
      for (int r = 0; r < 8; ++r) red[r][wv] = dp[r];
    }
    __syncthreads();
    if (tid < 8) {
      float d  = red[tid][0] + red[tid][1] + red[tid][2] + red[tid][3];
      float ep = 1.f / (1.f + __expf(-d));
      out_ep[(size_t)t * N + g * 8 + tid] = ep;
      float a = ws[WS_CHOICE + 2 * t] * ep + ws[WS_CHOICE + 2 * t + 1] * prevS[tid];
      prevS[tid] = ep;
      attnS[tid] = a;
      att[(size_t)t * N + g * 8 + tid] = a;
    }
    __syncthreads();
    float at[8];
#pragma unroll
    for (int r = 0; r < 8; ++r) at[r] = attnS[r];
    float4 pv = make_float4(0.f, 0.f, 0.f, 0.f);
#pragma unroll
    for (int r = 0; r < 8; ++r) {
      pv.x += at[r] * ev[r].x; pv.y += at[r] * ev[r].y;
      pv.z += at[r] * ev[r].z; pv.w += at[r] * ev[r].w;
    }
    float* acc = accum + (t % 3) * H;
    atomicAdd(acc + col + 0, pv.x);
    atomicAdd(acc + col + 1, pv.y);
    atomicAdd(acc + col + 2, pv.z);
    atomicAdd(acc + col + 3, pv.w);
    if (tid == 0) {
      float pa = 0.f;
#pragma unroll
      for (int r = 0; r < 8; ++r) pa += at[r];
      atomicAdd(asum + (t % 3), pa);
    }
    // ---- grid barrier: relaxed spin, acquire once on exit ----
    __syncthreads();
    target += (unsigned)gridDim.x;
    if (tid == 0) {
      __hip_atomic_fetch_add(ctr, 1u, __ATOMIC_RELEASE, __HIP_MEMORY_SCOPE_AGENT);
      while (__hip_atomic_load(ctr, __ATOMIC_RELAXED, __HIP_MEMORY_SCOPE_AGENT) < target) {}
      (void)__hip_atomic_load(ctr, __ATOMIC_ACQUIRE, __HIP_MEMORY_SCOPE_AGENT);
    }
    __syncthreads();
    // ---- phase 2: reduced bar_et -> kt; update ev registers ----
    float asv = __hip_atomic_load(asum + (t % 3), __ATOMIC_RELAXED, __HIP_MEMORY_SCOPE_AGENT);
    float4 pvs;
    pvs.x = __hip_atomic_load(acc + col + 0, __ATOMIC_RELAXED, __HIP_MEMORY_SCOPE_AGENT);
    pvs.y = __hip_atomic_load(acc + col + 1, __ATOMIC_RELAXED, __HIP_MEMORY_SCOPE_AGENT);
    pvs.z = __hip_atomic_load(acc + col + 2, __ATOMIC_RELAXED, __HIP_MEMORY_SCOPE_AGENT);
    pvs.w = __hip_atomic_load(acc + col + 3, __ATOMIC_RELAXED, __HIP_MEMORY_SCOPE_AGENT);
    float inv = 1.f / asv;
    float4 bar = make_float4(pvs.x * inv, pvs.y * inv, pvs.z * inv, pvs.w * inv);
    float sc = ws[WS_SCAL + t];
    float4 kt = make_float4(fmaxf(sc * bar.x, 0.f), fmaxf(sc * bar.y, 0.f),
                            fmaxf(sc * bar.z, 0.f), fmaxf(sc * bar.w, 0.f));
    if (g == 0) {
      *(float4*)(out_se + (size_t)t * H + col) = bar;
      *(float4*)(ktb + (size_t)t * H + col) = kt;
    }
    if (tid < 16)
      __hip_atomic_store(accum + ((t + 2) % 3) * H + g * 16 + tid, 0.f,
                         __ATOMIC_RELAXED, __HIP_MEMORY_SCOPE_AGENT);
    if (g == 0 && tid == 16)
      __hip_atomic_store(asum + ((t + 2) % 3), 0.f, __ATOMIC_RELAXED, __HIP_MEMORY_SCOPE_AGENT);
#pragma unroll
    for (int r = 0; r < 8; ++r) {
      float a = at[r];
      ev[r].x = a * kt.x + (1.f - a) * ev[r].x;
      ev[r].y = a * kt.y + (1.f - a) * ev[r].y;
      ev[r].z = a * kt.z + (1.f - a) * ev[r].z;
      ev[r].w = a * kt.w + (1.f - a) * ev[r].w;
    }
  }
}

// Reconstruct out_all[t,n,:] from ev0, attn, kt: per-row affine scan.
__global__ __launch_bounds__(256) void k_recon(
    const float* __restrict__ ev0, const float* __restrict__ att,
    const float* __restrict__ ktb, float* __restrict__ out_all) {
  const int n = blockIdx.x, tid = threadIdx.x;
  const int col = tid * 4;
  __shared__ float aS[S];
  if (tid < S) aS[tid] = att[(size_t)tid * N + n];
  float4 v = *(const float4*)(ev0 + (size_t)n * H + col);
  __syncthreads();
  for (int t = 0; t < S; ++t) {
    float a = aS[t];
    float4 k4 = *(const float4*)(ktb + (size_t)t * H + col);
    v.x = a * k4.x + (1.f - a) * v.x;
    v.y = a * k4.y + (1.f - a) * v.y;
    v.z = a * k4.z + (1.f - a) * v.z;
    v.w = a * k4.w + (1.f - a) * v.w;
    *(float4*)(out_all + ((size_t)t * N + n) * H + col) = v;
  }
}

extern "C" void kernel_launch(void* const* d_in, const int* in_sizes, int n_in,
                              void* d_out, int out_size, void* d_ws, size_t ws_size,
                              hipStream_t stream) {
  const float* vv  = (const float*)d_in[0];
  const float* ev0 = (const float*)d_in[1];
  const float* A1w = (const float*)d_in[2];
  const float* A1b = (const float*)d_in[3];
  const float* A2w = (const float*)d_in[4];
  const float* A2b = (const float*)d_in[5];
  const float* emb = (const float*)d_in[6];
  const float* W1w = (const float*)d_in[7];
  const float* W1b = (const float*)d_in[8];
  const float* W2w = (const float*)d_in[9];
  const float* W2b = (const float*)d_in[10];
  const float* W3w = (const float*)d_in[11];
  const float* W3b = (const float*)d_in[12];
  const float* W4w = (const float*)d_in[13];
  const float* W4b = (const float*)d_in[14];

  float* ws  = (float*)d_ws;
  float* out = (float*)d_out;
  float* out_ep  = out + OUT_EP;
  float* out_ac  = out + OUT_AC;
  float* out_se  = out + OUT_SE;
  float* out_all = out + OUT_ALL;
  float* out_act = out + OUT_ACT;
  float* cat = ws + WS_CAT;

  hipMemsetAsync(ws + WS_ACCUM, 0, (size_t)(3 * H + 5) * sizeof(float), stream);

  // Stage 1 (fused): Hall = relu(vv@A1w^T+A1b); hat = relu(vv@W1w^T+W1b)
  {
    GArgs a{};
    a.X = vv; a.ldx = H; a.K = H; a.act = 1;
    a.W0 = A1w; a.B0 = A1b; a.o1_0 = ws + WS_HALL; a.ld1_0 = H;   a.o2_0 = nullptr; a.ld2_0 = 0;
    a.W1 = W1w; a.B1 = W1b; a.o1_1 = cat;          a.ld1_1 = 1536; a.o2_1 = nullptr; a.ld2_1 = 0;
    gemmNT<<<dim3(16, 2), 256, 0, stream>>>(a);
  }
  // Stage 2: ac = sigmoid(Hall@A2w^T+A2b) -> out_ac and cat[:,1024:]
  {
    GArgs a{};
    a.X = ws + WS_HALL; a.ldx = H; a.K = H; a.act = 2;
    a.W0 = A2w; a.B0 = A2b; a.o1_0 = out_ac; a.ld1_0 = V; a.o2_0 = cat + H; a.ld2_0 = 1536;
    a.W1 = A2w; a.B1 = A2b; a.o1_1 = out_ac; a.ld1_1 = V; a.o2_1 = cat + H; a.ld2_1 = 1536;
    gemmNT<<<dim3(8, 1), 256, 0, stream>>>(a);
  }
  k_choice<<<S, 256, 0, stream>>>(cat, out_ac, W3w, W3b, ws);
  // Stage 3: w2v = cat@W2w^T + W2b
  {
    GArgs a{};
    a.X = cat; a.ldx = 1536; a.K = 1536; a.act = 0;
    a.W0 = W2w; a.B0 = W2b; a.o1_0 = ws + WS_W2V; a.ld1_0 = H; a.o2_0 = nullptr; a.ld2_0 = 0;
    a.W1 = W2w; a.B1 = W2b; a.o1_1 = ws + WS_W2V; a.ld1_1 = H; a.o2_1 = nullptr; a.ld2_1 = 0;
    gemmNT<<<dim3(16, 1), 256, 0, stream>>>(a);
  }
  k_barft<<<S, 256, 0, stream>>>(out_ac, emb, ws, W4w, W4b, out_act, ws);
  k_seq<<<64, 256, 0, stream>>>(ev0, ws, ws + WS_ACCUM, ws + WS_ASUM,
                                (unsigned*)(ws + WS_CTR),
                                ws + WS_ATT, ws + WS_KT, out_ep, out_se);
  k_recon<<<N, 256, 0, stream>>>(ev0, ws + WS_ATT, ws + WS_KT, out_all);
}